// Round 1
// baseline (473.533 us; speedup 1.0000x reference)
//
#include <hip/hip_runtime.h>
#include <math.h>

#define B 32
#define C 1536
#define D2 3072
#define L 1024
#define KC 256
#define XPAD 260   // LDS row pad (multiple of 4 for float4 alignment)
#define CH 16      // flash L-chunks -> grid 16x32, 64 wave-partials per b
#define LPW 16     // l's per wave = L/(CH*4)

__device__ inline float dot4(float4 a, float4 b) {
    return a.x * b.x + a.y * b.y + a.z * b.z + a.w * b.w;
}

// ---------------- copy x into feats[:, :C] ----------------
__global__ __launch_bounds__(256) void copy_x_k(const float* __restrict__ x,
                                                float* __restrict__ feats) {
    int i = blockIdx.x * 256 + threadIdx.x;   // over B*C
    int b = i / C, j = i % C;
    feats[b * D2 + j] = x[i];
}

// ---------------- 32x32 tiled transpose (for phi_w) ----------------
__global__ __launch_bounds__(256) void transpose_k(const float* __restrict__ src,
                                                   float* __restrict__ dst, int n) {
    __shared__ float tile[32][33];
    int bx = blockIdx.x * 32, by = blockIdx.y * 32;
    int tx = threadIdx.x & 31, ty0 = threadIdx.x >> 5;  // 8 rows per pass
    #pragma unroll
    for (int r = 0; r < 4; ++r) {
        int ty = ty0 + r * 8;
        tile[ty][tx] = src[(size_t)(by + ty) * n + bx + tx];
    }
    __syncthreads();
    #pragma unroll
    for (int r = 0; r < 4; ++r) {
        int ty = ty0 + r * 8;
        dst[(size_t)(bx + ty) * n + by + tx] = tile[tx][ty];
    }
}

// ---------------- split-K GEMM: part[kb][b][j] = sum_k A[b,k] W[j,k] ----------------
__global__ __launch_bounds__(256) void gemm32_splitk(const float* __restrict__ A,  // 32 x K
                                                     const float* __restrict__ W,  // N x K
                                                     float* __restrict__ part,     // ksplit x 32 x N
                                                     int N, int K) {
    __shared__ float xs[32 * XPAD];
    __shared__ float wsm[32 * XPAD];
    int tid = threadIdx.x;
    int j0 = blockIdx.x * 32;
    int kb = blockIdx.y;
    int k0 = kb * KC;

    #pragma unroll
    for (int r = 0; r < 8; ++r) {
        int f = tid + 256 * r;          // float4 index in [0,2048)
        int b = f >> 6, kq = f & 63;
        float4 v = *(const float4*)(A + (size_t)b * K + k0 + 4 * kq);
        *(float4*)(xs + b * XPAD + 4 * kq) = v;
    }
    #pragma unroll
    for (int r = 0; r < 8; ++r) {
        int f = tid + 256 * r;
        int j = f >> 6, kq = f & 63;
        float4 v = *(const float4*)(W + (size_t)(j0 + j) * K + k0 + 4 * kq);
        *(float4*)(wsm + j * XPAD + 4 * kq) = v;
    }
    __syncthreads();

    int bb = (tid & 15) * 2;
    int jj = (tid >> 4) * 2;
    const float* x0 = xs + bb * XPAD;
    const float* x1 = xs + (bb + 1) * XPAD;
    const float* w0 = wsm + jj * XPAD;
    const float* w1 = wsm + (jj + 1) * XPAD;
    float a00 = 0.f, a01 = 0.f, a10 = 0.f, a11 = 0.f;
    #pragma unroll 8
    for (int k = 0; k < KC; k += 4) {
        float4 xa = *(const float4*)(x0 + k);
        float4 xb = *(const float4*)(x1 + k);
        float4 wa = *(const float4*)(w0 + k);
        float4 wb = *(const float4*)(w1 + k);
        a00 += dot4(xa, wa); a01 += dot4(xa, wb);
        a10 += dot4(xb, wa); a11 += dot4(xb, wb);
    }
    float* p = part + (size_t)kb * 32 * N;
    p[(size_t)bb * N + j0 + jj]           = a00;
    p[(size_t)bb * N + j0 + jj + 1]       = a01;
    p[(size_t)(bb + 1) * N + j0 + jj]     = a10;
    p[(size_t)(bb + 1) * N + j0 + jj + 1] = a11;
}

// ---------------- split-K reduce + epilogues ----------------
// mode 0: out = sum + bias (bias may be null)
// mode 2: feats[b*D2 + C + j] = sum + bias[j] + x[b*C+j]
// mode 3: out = relu(sum + bias)
__global__ __launch_bounds__(256) void reduce_part(const float* __restrict__ part,
                                                   const float* __restrict__ bias,
                                                   const float* __restrict__ addx,
                                                   float* __restrict__ out,
                                                   float* __restrict__ feats,
                                                   int N, int ksplit, int mode) {
    int i = blockIdx.x * 256 + threadIdx.x;   // over 32*N
    int b = i / N, j = i % N;
    float s = 0.f;
    for (int kk = 0; kk < ksplit; ++kk) s += part[(size_t)kk * 32 * N + i];
    if (bias) s += bias[j];
    if (mode == 2) {
        feats[(size_t)b * D2 + C + j] = s + addx[(size_t)b * C + j];
    } else if (mode == 3) {
        out[i] = fmaxf(s, 0.f);
    } else {
        out[i] = s;
    }
}

// ---------------- flash: scores + online softmax + weighted lfb accumulation ----------------
__global__ __launch_bounds__(256) void flash_k(const float* __restrict__ u,    // 32 x C
                                               const float* __restrict__ lfb,  // 32 x L x C
                                               float* __restrict__ pm,
                                               float* __restrict__ ps,
                                               float* __restrict__ pv) {
    int chunk = blockIdx.x;          // 0..CH-1
    int b = blockIdx.y;              // 0..31
    int wave = threadIdx.x >> 6;     // 0..3
    int lane = threadIdx.x & 63;
    int widx = chunk * 4 + wave;     // 0..63

    const float scale = 39.19183588453085f;  // sqrt(1536)

    float uu[24];
    const float* ub = u + (size_t)b * C;
    #pragma unroll
    for (int t = 0; t < 6; ++t)
        *(float4*)(uu + 4 * t) = *(const float4*)(ub + 4 * lane + 256 * t);

    float m = -INFINITY, s = 0.f;
    float vv[24];
    #pragma unroll
    for (int t = 0; t < 24; ++t) vv[t] = 0.f;

    int l0 = chunk * (L / CH) + wave;        // stride 4 within chunk
    for (int i = 0; i < LPW; ++i) {
        int l = l0 + i * 4;
        const float* row = lfb + ((size_t)b * L + l) * C;
        float xx[24];
        #pragma unroll
        for (int t = 0; t < 6; ++t)
            *(float4*)(xx + 4 * t) = *(const float4*)(row + 4 * lane + 256 * t);
        float d = 0.f;
        #pragma unroll
        for (int t = 0; t < 24; ++t) d += xx[t] * uu[t];
        #pragma unroll
        for (int off = 32; off > 0; off >>= 1) d += __shfl_xor(d, off, 64);
        float score = d * scale;
        float mn = fmaxf(m, score);
        float alpha = __expf(m - mn);        // 0 when m == -inf
        float p = __expf(score - mn);
        s = s * alpha + p;
        #pragma unroll
        for (int t = 0; t < 24; ++t) vv[t] = vv[t] * alpha + p * xx[t];
        m = mn;
    }

    if (lane == 0) { pm[b * 64 + widx] = m; ps[b * 64 + widx] = s; }
    float* pvb = pv + ((size_t)b * 64 + widx) * C;
    #pragma unroll
    for (int t = 0; t < 6; ++t)
        *(float4*)(pvb + 4 * lane + 256 * t) = *(const float4*)(vv + 4 * t);
}

// ---------------- combine wave-partials -> v[b][c] ----------------
__global__ __launch_bounds__(256) void combine_k(const float* __restrict__ pm,
                                                 const float* __restrict__ ps,
                                                 const float* __restrict__ pv,
                                                 float* __restrict__ v) {
    int b = blockIdx.x;
    int tid = threadIdx.x;
    __shared__ float coef[64];
    if (tid < 64) {
        float mj = pm[b * 64 + tid];
        float M = mj;
        #pragma unroll
        for (int off = 32; off > 0; off >>= 1) M = fmaxf(M, __shfl_xor(M, off, 64));
        float ej = expf(mj - M);
        float S = ps[b * 64 + tid] * ej;
        #pragma unroll
        for (int off = 32; off > 0; off >>= 1) S += __shfl_xor(S, off, 64);
        coef[tid] = ej / S;
    }
    __syncthreads();
    for (int c = tid; c < C; c += 256) {
        float acc = 0.f;
        #pragma unroll 8
        for (int j = 0; j < 64; ++j)
            acc += coef[j] * pv[((size_t)b * 64 + j) * C + c];
        v[(size_t)b * C + c] = acc;
    }
}

// ---------------- layernorm + relu on o (32 rows) ----------------
__global__ __launch_bounds__(256) void ln_relu_k(const float* __restrict__ o,
                                                 const float* __restrict__ g,
                                                 const float* __restrict__ bt,
                                                 float* __restrict__ out) {
    int b = blockIdx.x, tid = threadIdx.x;
    __shared__ float r1[4], r2[4];
    const float* ob = o + (size_t)b * C;
    float lv[6];
    float s1 = 0.f, s2 = 0.f;
    #pragma unroll
    for (int t = 0; t < 6; ++t) {
        float x = ob[tid + 256 * t];
        lv[t] = x; s1 += x; s2 += x * x;
    }
    #pragma unroll
    for (int off = 32; off > 0; off >>= 1) {
        s1 += __shfl_xor(s1, off, 64);
        s2 += __shfl_xor(s2, off, 64);
    }
    int wave = tid >> 6, lane = tid & 63;
    if (lane == 0) { r1[wave] = s1; r2[wave] = s2; }
    __syncthreads();
    s1 = r1[0] + r1[1] + r1[2] + r1[3];
    s2 = r2[0] + r2[1] + r2[2] + r2[3];
    float mu = s1 / (float)C;
    float var = s2 / (float)C - mu * mu;
    float rstd = 1.0f / sqrtf(var + 1e-5f);
    #pragma unroll
    for (int t = 0; t < 6; ++t) {
        int c = tid + 256 * t;
        float y = (lv[t] - mu) * rstd * g[c] + bt[c];
        out[(size_t)b * C + c] = fmaxf(y, 0.f);
    }
}

// ---------------- final 4 heads ----------------
__global__ __launch_bounds__(256) void heads_k(const float* __restrict__ h,
                                               const float* __restrict__ w1, const float* __restrict__ b1,
                                               const float* __restrict__ w2, const float* __restrict__ b2,
                                               const float* __restrict__ w3, const float* __restrict__ b3,
                                               const float* __restrict__ wt, const float* __restrict__ bt,
                                               float* __restrict__ out) {
    int b = blockIdx.x;
    int wave = threadIdx.x >> 6, lane = threadIdx.x & 63;
    const float* hb = h + (size_t)b * D2;
    float acc = 0.f;
    if (wave < 3) {
        const float* w = (wave == 0) ? w1 : ((wave == 1) ? w2 : w3);
        const float* hh = hb + wave * 1024;
        #pragma unroll
        for (int t = 0; t < 16; ++t) acc += hh[lane + 64 * t] * w[lane + 64 * t];
    } else {
        #pragma unroll
        for (int t = 0; t < 48; ++t) acc += hb[lane + 64 * t] * wt[lane + 64 * t];
    }
    #pragma unroll
    for (int off = 32; off > 0; off >>= 1) acc += __shfl_xor(acc, off, 64);
    if (lane == 0) {
        float bias = (wave == 0) ? b1[0] : (wave == 1) ? b2[0] : (wave == 2) ? b3[0] : bt[0];
        out[b * 4 + wave] = acc + bias;
    }
}

extern "C" void kernel_launch(void* const* d_in, const int* in_sizes, int n_in,
                              void* d_out, int out_size, void* d_ws, size_t ws_size,
                              hipStream_t stream) {
    (void)in_sizes; (void)n_in; (void)out_size; (void)ws_size;
    const float* x       = (const float*)d_in[0];
    const float* lfb     = (const float*)d_in[1];
    const float* theta_w = (const float*)d_in[2];
    const float* theta_b = (const float*)d_in[3];
    const float* phi_w   = (const float*)d_in[4];
    // d_in[5] = phi_b: additive constant per softmax row -> drops out
    const float* gi_w    = (const float*)d_in[6];
    const float* gi_b    = (const float*)d_in[7];
    const float* ln_g    = (const float*)d_in[8];
    const float* ln_b    = (const float*)d_in[9];
    const float* fc_w    = (const float*)d_in[10];
    const float* fc_b    = (const float*)d_in[11];
    const float* fcn_w   = (const float*)d_in[12];
    const float* fcn_b   = (const float*)d_in[13];
    const float* w1 = (const float*)d_in[14]; const float* b1 = (const float*)d_in[15];
    const float* w2 = (const float*)d_in[16]; const float* b2 = (const float*)d_in[17];
    const float* w3 = (const float*)d_in[18]; const float* b3 = (const float*)d_in[19];
    const float* wt = (const float*)d_in[20]; const float* bt = (const float*)d_in[21];
    float* out = (float*)d_out;
    float* w = (float*)d_ws;

    // workspace layout (floats). pm/ps/pv alias part+phiT (disjoint lifetimes).
    float* theta = w;                  // 49152
    float* u     = w + 49152;          // 49152
    float* part  = w + 98304;          // up to 12*32*3072 = 1179648
    float* phiT  = w + 1277952;        // 2359296
    float* pm    = w + 98304;          // 2048   (alias, used after u is done)
    float* ps    = w + 100352;         // 2048
    float* pv    = w + 102400;         // 3145728 (ends 3248128 <= 3637248)
    float* vbuf  = w + 3637248;        // 49152
    float* obuf  = w + 3686400;        // 49152
    float* oln   = w + 3735552;        // 49152
    float* feats = w + 3784704;        // 98304
    float* h     = w + 3883008;        // 98304  (total 3981312 floats ~ 15.2 MiB)

    copy_x_k<<<192, 256, 0, stream>>>(x, feats);
    transpose_k<<<dim3(48, 48), 256, 0, stream>>>(phi_w, phiT, C);

    // theta = x @ theta_w.T + theta_b
    gemm32_splitk<<<dim3(48, 6), 256, 0, stream>>>(x, theta_w, part, C, C);
    reduce_part<<<192, 256, 0, stream>>>(part, theta_b, nullptr, theta, nullptr, C, 6, 0);

    // u = theta @ phi_w  (= theta @ (phi_w^T)^T)
    gemm32_splitk<<<dim3(48, 6), 256, 0, stream>>>(theta, phiT, part, C, C);
    reduce_part<<<192, 256, 0, stream>>>(part, nullptr, nullptr, u, nullptr, C, 6, 0);

    // flash pass over lfb: scores -> online softmax -> weighted sum partials
    flash_k<<<dim3(CH, B), 256, 0, stream>>>(u, lfb, pm, ps, pv);
    combine_k<<<B, 256, 0, stream>>>(pm, ps, pv, vbuf);

    // o = v @ gi_w.T + gi_b
    gemm32_splitk<<<dim3(48, 6), 256, 0, stream>>>(vbuf, gi_w, part, C, C);
    reduce_part<<<192, 256, 0, stream>>>(part, gi_b, nullptr, obuf, nullptr, C, 6, 0);

    // relu(layernorm(o))
    ln_relu_k<<<B, 256, 0, stream>>>(obuf, ln_g, ln_b, oln);

    // o2 = oln @ fc_w.T + fc_b ; feats[:, C:] = o2 + x
    gemm32_splitk<<<dim3(48, 6), 256, 0, stream>>>(oln, fc_w, part, C, C);
    reduce_part<<<192, 256, 0, stream>>>(part, fc_b, x, nullptr, feats, C, 6, 2);

    // h = relu(feats @ fc_nlb_w.T + fc_nlb_b)
    gemm32_splitk<<<dim3(96, 12), 256, 0, stream>>>(feats, fcn_w, part, D2, D2);
    reduce_part<<<384, 256, 0, stream>>>(part, fcn_b, nullptr, h, nullptr, D2, 12, 3);

    // heads
    heads_k<<<B, 256, 0, stream>>>(h, w1, b1, w2, b2, w3, b3, wt, bt, out);
}